// Round 13
// baseline (445.909 us; speedup 1.0000x reference)
//
#include <hip/hip_runtime.h>
#include <math.h>

#define NSTEPS 128
#define BATCH  32768
#define HID    64
#define BLK    512

constexpr float DTf = 1.0f / 128.0f;
constexpr float TWO_LOG2E = 2.88539008177792681f;

typedef float v2f __attribute__((ext_vector_type(2)));

__device__ __forceinline__ v2f v2ld(const float* p) { return *(const v2f*)p; }

// Force a provably wave-uniform pointer -> compiler emits s_load (SMEM),
// removing per-lane vector loads + address arithmetic from the VALU stream.
__device__ __forceinline__ const float* uni(const float* p) {
    uint64_t v  = (uint64_t)(uintptr_t)p;
    uint32_t lo = __builtin_amdgcn_readfirstlane((uint32_t)v);
    uint32_t hi = __builtin_amdgcn_readfirstlane((uint32_t)(v >> 32));
    return (const float*)(uintptr_t)(((uint64_t)hi << 32) | lo);
}

struct CD { float c, dre, dim; };

// scalar tanh via hw exp2 + rcp (saturates exactly)
__device__ __forceinline__ float fast_tanh(float x) {
    float e = __builtin_amdgcn_exp2f(x * TWO_LOG2E);
    return 1.0f - 2.0f * __builtin_amdgcn_rcpf(e + 1.0f);
}
// packed-pair tanh: VALU parts pack, exp2/rcp per component
__device__ __forceinline__ v2f fast_tanh2(v2f z) {
    v2f zs = z * TWO_LOG2E;
    v2f e;
    e.x = __builtin_amdgcn_exp2f(zs.x);
    e.y = __builtin_amdgcn_exp2f(zs.y);
    v2f e1 = e + 1.0f;
    v2f r;
    r.x = __builtin_amdgcn_rcpf(e1.x);
    r.y = __builtin_amdgcn_rcpf(e1.y);
    return 1.0f - 2.0f * r;
}

// ---- grad MLP: 5 -> 64 -> 6, packed pairs ----
__device__ __forceinline__ void grad_mlp(
    float n, float x0, float x1, float x2, float p,
    const float* __restrict__ w1, const float* __restrict__ b1,
    const float* __restrict__ w2, const float* __restrict__ b2,
    float& og0, float& og1, float& og2, float& og3, float& og4, float& og5)
{
    v2f og01 = { b2[0], b2[1] };
    v2f og23 = { b2[2], b2[3] };
    v2f og45 = { b2[4], b2[5] };
#pragma unroll 4
    for (int j = 0; j < HID; j += 2) {
        v2f z = n  * v2ld(w1 + j)
              + x0 * v2ld(w1 + HID   + j)
              + x1 * v2ld(w1 + 2*HID + j)
              + x2 * v2ld(w1 + 3*HID + j)
              + p  * v2ld(w1 + 4*HID + j)
              + v2ld(b1 + j);
        v2f h = fast_tanh2(z);
        const float* wj = w2 + j*6;
        og01 += h.x * v2ld(wj)     + h.y * v2ld(wj + 6);
        og23 += h.x * v2ld(wj + 2) + h.y * v2ld(wj + 8);
        og45 += h.x * v2ld(wj + 4) + h.y * v2ld(wj + 10);
    }
    og0 = og01.x; og1 = og01.y; og2 = og23.x;
    og3 = og23.y; og4 = og45.x; og5 = og45.y;
}

// ---- jump MLP, double-sided (3-op identity form) ----
template<bool USE_TD>
__device__ __forceinline__ void jump_mlp(
    float n, float x0, float x1, float x2, float p,
    const float* __restrict__ v1, const float* __restrict__ c1,
    const float* __restrict__ vw2, const float* __restrict__ Td,
    float& dup0, float& dup1, float& dum0, float& dum1)
{
    v2f dup01 = { 0.f, 0.f };
    v2f dum01 = { 0.f, 0.f };
#pragma unroll 4
    for (int j = 0; j < HID; j += 2) {
        v2f d  = v2ld(v1 + j);
        v2f zb = n  * d
               + x0 * v2ld(v1 + HID   + j)
               + x1 * v2ld(v1 + 2*HID + j)
               + x2 * v2ld(v1 + 3*HID + j)
               + p  * v2ld(v1 + 4*HID + j)
               + v2ld(c1 + j);
        v2f T  = fast_tanh2(zb);
        v2f Tv;
        if (USE_TD) Tv = v2ld(Td + j);
        else { Tv.x = fast_tanh(d.x); Tv.y = fast_tanh(d.y); }
        v2f a    = T * Tv;
        v2f oma2 = 1.0f - a*a;
        v2f r;
        r.x = __builtin_amdgcn_rcpf(oma2.x);
        r.y = __builtin_amdgcn_rcpf(oma2.y);
        v2f s1 = (T + Tv) * r;
        v2f u1 = s1 - T;
        v2f ep = u1 - s1*a;                 // (T+Tv)(1-a)r - T
        v2f s2 = (T - Tv) * r;
        v2f u2 = s2 - T;
        v2f em = u2 + s2*a;                 // (T-Tv)(1+a)r - T
        v2f wv0 = v2ld(vw2 + 2*j);
        v2f wv1 = v2ld(vw2 + 2*j + 2);
        dup01 += ep.x * wv0 + ep.y * wv1;
        dum01 += em.x * wv0 + em.y * wv1;
    }
    dup0 = dup01.x; dup1 = dup01.y;
    dum0 = dum01.x; dum1 = dum01.y;
}

// ---- jump MLP, single-sided: e = tanh(zb + sgn*d) - tanh(zb), sgn = dN = +-1 ----
__device__ __forceinline__ void jump_mlp_1s(
    float n, float x0, float x1, float x2, float p, float sgn,
    const float* __restrict__ v1, const float* __restrict__ c1,
    const float* __restrict__ vw2, const float* __restrict__ Td,
    float& e0, float& e1)
{
    v2f acc = { 0.f, 0.f };
#pragma unroll 4
    for (int j = 0; j < HID; j += 2) {
        v2f d  = v2ld(v1 + j);
        v2f zb = n  * d
               + x0 * v2ld(v1 + HID   + j)
               + x1 * v2ld(v1 + 2*HID + j)
               + x2 * v2ld(v1 + 3*HID + j)
               + p  * v2ld(v1 + 4*HID + j)
               + v2ld(c1 + j);
        v2f T   = fast_tanh2(zb);
        v2f Tsv = sgn * v2ld(Td + j);       // tanh(sgn*d) = sgn*tanh(d)
        v2f as  = T * Tsv;
        v2f oma = 1.0f - as*as;
        v2f r;
        r.x = __builtin_amdgcn_rcpf(oma.x);
        r.y = __builtin_amdgcn_rcpf(oma.y);
        v2f s1 = (T + Tsv) * r;
        v2f u1 = s1 - T;
        v2f e  = u1 - s1*as;                // (T+Tsv)(1-as)r - T
        acc += e.x * v2ld(vw2 + 2*j) + e.y * v2ld(vw2 + 2*j + 2);
    }
    e0 = acc.x; e1 = acc.y;
}

// Full step (fallback path)
template<bool USE_TD>
__device__ __forceinline__ CD step_core(
    float n, float x0, float x1, float x2, float p, float t,
    float db0, float db1, float db2, float dN, float phi,
    const float* __restrict__ w1, const float* __restrict__ b1,
    const float* __restrict__ w2, const float* __restrict__ b2,
    const float* __restrict__ v1, const float* __restrict__ c1,
    const float* __restrict__ vw2, const float* __restrict__ Td)
{
    float og0, og1, og2, og3, og4, og5;
    grad_mlp(n,x0,x1,x2,p, w1,b1,w2,b2, og0,og1,og2,og3,og4,og5);
    float dup0, dup1, dum0, dum1;
    jump_mlp<USE_TD>(n,x0,x1,x2,p, v1,c1,vw2,Td, dup0,dup1,dum0,dum1);

    float r2    = fmaf(x0,x0, fmaf(x1,x1, x2*x2));
    float gamma = 0.1f - (0.5f + 0.1f*r2) * __builtin_amdgcn_rcpf(1.0f + r2);
    float xdb   = fmaf(x0,db0, fmaf(x1,db1, x2*db2));
    float kc    = sqrtf(fmaf(0.2f, fabsf(n), 1.0f));
    float gdb_r = fmaf(og0,db0, fmaf(og1,db1, og2*db2));
    float gdb_i = fmaf(og3,db0, fmaf(og4,db1, og5*db2));
    float gx_r  = fmaf(og0,x0,  fmaf(og1,x1,  og2*x2));
    float gx_i  = fmaf(og3,x0,  fmaf(og4,x1,  og5*x2));
    float gb_r  = kc * fmaf(gamma*xdb, gx_r, 0.5f*gdb_r);
    float gb_i  = kc * fmaf(gamma*xdb, gx_i, 0.5f*gdb_i);

    float alpha = 0.5f*(n + 1.0f);
    float beta  = fmaf(0.4f, fabsf(n), 0.1f);
    float cf    = 0.1f*(1.0f + t)*DTf;
    float d0r = gb_r - (alpha*dup0 + beta*dum0)*DTf - cf*(og0+og1+og2);
    float d0i = gb_i - (alpha*dup1 + beta*dum1)*DTf - cf*(og3+og4+og5);

    float c, sr, si;
    if (dN > 0.5f)       { c = 1.0f;          sr = dup0; si = dup1; }
    else if (dN < -0.5f) { c = 1.0f;          sr = dum0; si = dum1; }
    else                 { c = 1.0f - p*DTf;  sr = d0r;  si = d0i;  }

    float sp, cp;
    __sincosf(phi, &sp, &cp);
    CD o;
    o.c   = c;
    o.dre = fmaf(cp, sr,  sp*si);
    o.dim = fmaf(cp, si, -sp*sr);
    return o;
}

__device__ __forceinline__ void mlp_u0(
    float n, float x0, float x1, float x2, float p,
    const float* __restrict__ w1, const float* __restrict__ b1,
    const float* __restrict__ w2, const float* __restrict__ b2,
    float& ur, float& ui)
{
    v2f o01 = { b2[0], b2[1] };
#pragma unroll 4
    for (int j = 0; j < HID; j += 2) {
        v2f z = n  * v2ld(w1 + j)
              + x0 * v2ld(w1 + HID   + j)
              + x1 * v2ld(w1 + 2*HID + j)
              + x2 * v2ld(w1 + 3*HID + j)
              + p  * v2ld(w1 + 4*HID + j)
              + v2ld(b1 + j);
        v2f h = fast_tanh2(z);
        o01 += h.x * v2ld(w2 + 2*j) + h.y * v2ld(w2 + 2*j + 2);
    }
    ur = o01.x; ui = o01.y;
}

// ---- Pass 1: phi prefix ----
__global__ void __launch_bounds__(256) k_phi(
    const float* __restrict__ X, const float* __restrict__ P,
    float* __restrict__ phi, float* __restrict__ phiF)
{
    int b = blockIdx.x*256 + threadIdx.x;
    double s = 0.0;
    for (int k = 0; k < NSTEPS; k++) {
        size_t idx = (size_t)k*BATCH + b;
        phi[idx] = (float)(DTf * s);
        float p = P[idx];
        const float* xp = X + idx*3;
        float x0 = xp[0], x1 = xp[1], x2 = xp[2];
        s += (double)p * (double)(x0*x0 + x1*x1 + x2*x2);
    }
    phiF[b] = (float)(DTf * s);
}

// ---- Pass 2: compacted, class-specialized per-wave; SGPR weight bases ----
__global__ void __launch_bounds__(BLK) k_step(
    const float* __restrict__ N,  const float* __restrict__ X,
    const float* __restrict__ P,  const float* __restrict__ Tarr,
    const float* __restrict__ dB,
    const float* __restrict__ Wg1, const float* __restrict__ bg1,
    const float* __restrict__ Wg2, const float* __restrict__ bg2,
    const float* __restrict__ Wj1, const float* __restrict__ bj1,
    const float* __restrict__ Wj2, const float* __restrict__ bj2,
    const float* __restrict__ phiA, float* __restrict__ cA, float2* __restrict__ dA)
{
    int k = blockIdx.y;
    const float* w1  = uni(Wg1 + k*5*HID);
    const float* b1  = uni(bg1 + k*HID);
    const float* w2  = uni(Wg2 + k*HID*6);
    const float* b2  = uni(bg2 + k*6);
    const float* v1  = uni(Wj1 + k*5*HID);
    const float* c1  = uni(bj1 + k*HID);
    const float* vw2 = uni(Wj2 + k*HID*2);
    float t = Tarr[k];

    __shared__ float Td[HID];
    __shared__ float sdat[BLK][13];             // stride 13: conflict-benign
    __shared__ int   sorig[BLK];
    __shared__ int   cnt[2];
    if (threadIdx.x < HID) Td[threadIdx.x] = fast_tanh(v1[threadIdx.x]);
    if (threadIdx.x == 0) { cnt[0] = 0; cnt[1] = 0; }
    __syncthreads();

    int tid = threadIdx.x;
    int b = blockIdx.x*BLK + tid;
    size_t idx = (size_t)k*BATCH + b;
    {
        float n  = N[idx], p = P[idx];
        const float* xp  = X  + idx*3;
        const float* dbp = dB + idx*3;
        float dN = N[idx + BATCH] - n;          // exact +-1/0 in fp32
        bool full = (dN == 0.0f);
        int pos = full ? atomicAdd(&cnt[0], 1) : (BLK-1) - atomicAdd(&cnt[1], 1);
        sorig[pos]  = b;
        float* sd = sdat[pos];
        sd[0]=n;      sd[1]=p;      sd[2]=xp[0]; sd[3]=xp[1]; sd[4]=xp[2];
        sd[5]=dbp[0]; sd[6]=dbp[1]; sd[7]=dbp[2];
        sd[8]=phiA[idx]; sd[9]=dN;
    }
    __syncthreads();

    const float* md = sdat[tid];
    float n   = md[0], p   = md[1];
    float x0  = md[2], x1  = md[3], x2 = md[4];
    float db0 = md[5], db1 = md[6], db2 = md[7];
    float phi = md[8], dN  = md[9];
    int   ob  = sorig[tid];
    bool  g   = (dN == 0.0f);

    float c, sr, si;
    if (__ballot(g) != 0ull) {
        // ---- full / mixed wave ----
        float dup0, dup1, dum0, dum1;
        jump_mlp<true>(n,x0,x1,x2,p, v1,c1,vw2,Td, dup0,dup1,dum0,dum1);
        float og0, og1, og2, og3, og4, og5;
        grad_mlp(n,x0,x1,x2,p, w1,b1,w2,b2, og0,og1,og2,og3,og4,og5);

        float r2    = fmaf(x0,x0, fmaf(x1,x1, x2*x2));
        float gamma = 0.1f - (0.5f + 0.1f*r2) * __builtin_amdgcn_rcpf(1.0f + r2);
        float xdb   = fmaf(x0,db0, fmaf(x1,db1, x2*db2));
        float kc    = sqrtf(fmaf(0.2f, fabsf(n), 1.0f));
        float gdb_r = fmaf(og0,db0, fmaf(og1,db1, og2*db2));
        float gdb_i = fmaf(og3,db0, fmaf(og4,db1, og5*db2));
        float gx_r  = fmaf(og0,x0,  fmaf(og1,x1,  og2*x2));
        float gx_i  = fmaf(og3,x0,  fmaf(og4,x1,  og5*x2));
        float gb_r  = kc * fmaf(gamma*xdb, gx_r, 0.5f*gdb_r);
        float gb_i  = kc * fmaf(gamma*xdb, gx_i, 0.5f*gdb_i);

        float alpha = 0.5f*(n + 1.0f);
        float beta  = fmaf(0.4f, fabsf(n), 0.1f);
        float cf    = 0.1f*(1.0f + t)*DTf;
        float d0r = gb_r - (alpha*dup0 + beta*dum0)*DTf - cf*(og0+og1+og2);
        float d0i = gb_i - (alpha*dup1 + beta*dum1)*DTf - cf*(og3+og4+og5);

        if (dN > 0.5f)       { c = 1.0f;          sr = dup0; si = dup1; }
        else if (dN < -0.5f) { c = 1.0f;          sr = dum0; si = dum1; }
        else                 { c = 1.0f - p*DTf;  sr = d0r;  si = d0i;  }
    } else {
        // ---- pure jump wave: single-sided, no grad ----
        jump_mlp_1s(n,x0,x1,x2,p, dN, v1,c1,vw2,Td, sr, si);
        c = 1.0f;
    }

    float sp, cp;
    __sincosf(phi, &sp, &cp);
    size_t oidx = (size_t)k*BATCH + ob;
    cA[oidx] = c;
    dA[oidx] = make_float2(fmaf(cp, sr,  sp*si), fmaf(cp, si, -sp*sr));
}

// ---- Pass 3: u0 MLP + affine fold + g ----
__global__ void __launch_bounds__(256) k_combine(
    const float* __restrict__ N, const float* __restrict__ X, const float* __restrict__ P,
    const float* __restrict__ Wr1, const float* __restrict__ br1,
    const float* __restrict__ Wr2, const float* __restrict__ br2,
    const float* __restrict__ cA, const float2* __restrict__ dA,
    const float* __restrict__ phiF, float* __restrict__ out, int full)
{
    int b = blockIdx.x*256 + threadIdx.x;
    const float* xp = X + (size_t)b*3;
    float ur, ui;
    mlp_u0(N[b], xp[0], xp[1], xp[2], P[b], Wr1, br1, Wr2, br2, ur, ui);
#pragma unroll 8
    for (int k = 0; k < NSTEPS; k++) {
        size_t idx = (size_t)k*BATCH + b;
        float  c = cA[idx];
        float2 d = dA[idx];
        ur = fmaf(c, ur, d.x);
        ui = fmaf(c, ui, d.y);
    }
    float phi = phiF[b];
    const float* xf = X + ((size_t)NSTEPS*BATCH + b)*3;
    float s = xf[0] + xf[1] + xf[2];
    float sp, cp;
    __sincosf(phi, &sp, &cp);
    float gre =  s*cp;
    float gim = -s*sp;
    if (full) {
        out[b]           = ur;
        out[BATCH + b]   = ui;
        out[2*BATCH + b] = gre;
        out[3*BATCH + b] = gim;
    } else {
        out[b]         = ur;
        out[BATCH + b] = gre;
    }
}

// ---- Fallback (no workspace) ----
__global__ void __launch_bounds__(256) k_fused(
    const float* __restrict__ N,  const float* __restrict__ X,
    const float* __restrict__ P,  const float* __restrict__ Tarr,
    const float* __restrict__ dB,
    const float* __restrict__ Wr1, const float* __restrict__ br1,
    const float* __restrict__ Wr2, const float* __restrict__ br2,
    const float* __restrict__ Wg1, const float* __restrict__ bg1,
    const float* __restrict__ Wg2, const float* __restrict__ bg2,
    const float* __restrict__ Wj1, const float* __restrict__ bj1,
    const float* __restrict__ Wj2, const float* __restrict__ bj2,
    float* __restrict__ out, int full)
{
    int b = blockIdx.x*256 + threadIdx.x;
    float ur, ui;
    {
        const float* xp = X + (size_t)b*3;
        mlp_u0(N[b], xp[0], xp[1], xp[2], P[b], Wr1, br1, Wr2, br2, ur, ui);
    }
    double s = 0.0;
    for (int k = 0; k < NSTEPS; k++) {
        size_t idx = (size_t)k*BATCH + b;
        float n = N[idx], p = P[idx], t = Tarr[k];
        const float* xp  = X  + idx*3;
        const float* dbp = dB + idx*3;
        float dN  = N[idx + BATCH] - n;
        float phi = (float)(DTf * s);
        CD cd = step_core<false>(n, xp[0], xp[1], xp[2], p, t,
                                 dbp[0], dbp[1], dbp[2], dN, phi,
                                 Wg1 + k*5*HID, bg1 + k*HID,
                                 Wg2 + k*HID*6, bg2 + k*6,
                                 Wj1 + k*5*HID, bj1 + k*HID,
                                 Wj2 + k*HID*2, nullptr);
        ur = fmaf(cd.c, ur, cd.dre);
        ui = fmaf(cd.c, ui, cd.dim);
        float x0 = xp[0], x1 = xp[1], x2 = xp[2];
        s += (double)p * (double)(x0*x0 + x1*x1 + x2*x2);
    }
    float phi = (float)(DTf * s);
    const float* xf = X + ((size_t)NSTEPS*BATCH + b)*3;
    float sm = xf[0] + xf[1] + xf[2];
    float sp, cp;
    __sincosf(phi, &sp, &cp);
    float gre =  sm*cp;
    float gim = -sm*sp;
    if (full) {
        out[b]           = ur;
        out[BATCH + b]   = ui;
        out[2*BATCH + b] = gre;
        out[3*BATCH + b] = gim;
    } else {
        out[b]         = ur;
        out[BATCH + b] = gre;
    }
}

extern "C" void kernel_launch(void* const* d_in, const int* in_sizes, int n_in,
                              void* d_out, int out_size, void* d_ws, size_t ws_size,
                              hipStream_t stream)
{
    const float* N    = (const float*)d_in[0];
    const float* X    = (const float*)d_in[1];
    const float* P    = (const float*)d_in[2];
    const float* Tarr = (const float*)d_in[3];
    const float* dB   = (const float*)d_in[4];
    const float* Wr1  = (const float*)d_in[5];
    const float* br1  = (const float*)d_in[6];
    const float* Wr2  = (const float*)d_in[7];
    const float* br2  = (const float*)d_in[8];
    const float* Wg1  = (const float*)d_in[9];
    const float* bg1  = (const float*)d_in[10];
    const float* Wg2  = (const float*)d_in[11];
    const float* bg2  = (const float*)d_in[12];
    const float* Wj1  = (const float*)d_in[13];
    const float* bj1  = (const float*)d_in[14];
    const float* Wj2  = (const float*)d_in[15];
    const float* bj2  = (const float*)d_in[16];
    float* out = (float*)d_out;

    const int full = (out_size >= 4*BATCH) ? 1 : 0;

    const size_t phi_elems = (size_t)NSTEPS*BATCH;
    const size_t need = (phi_elems + BATCH + phi_elems)*sizeof(float)
                      + phi_elems*sizeof(float2);

    if (ws_size >= need) {
        float*  phiA = (float*)d_ws;
        float*  phiF = phiA + phi_elems;
        float*  cA   = phiF + BATCH;
        float2* dA   = (float2*)(cA + phi_elems);

        k_phi<<<dim3(BATCH/256), dim3(256), 0, stream>>>(X, P, phiA, phiF);
        k_step<<<dim3(BATCH/BLK, NSTEPS), dim3(BLK), 0, stream>>>(
            N, X, P, Tarr, dB, Wg1, bg1, Wg2, bg2, Wj1, bj1, Wj2, bj2,
            phiA, cA, dA);
        k_combine<<<dim3(BATCH/256), dim3(256), 0, stream>>>(
            N, X, P, Wr1, br1, Wr2, br2, cA, dA, phiF, out, full);
    } else {
        k_fused<<<dim3(BATCH/256), dim3(256), 0, stream>>>(
            N, X, P, Tarr, dB, Wr1, br1, Wr2, br2,
            Wg1, bg1, Wg2, bg2, Wj1, bj1, Wj2, bj2, out, full);
    }
}

// Round 14
// 217.952 us; speedup vs baseline: 2.0459x; 2.0459x over previous
//
#include <hip/hip_runtime.h>
#include <math.h>

#define NSTEPS 128
#define BATCH  32768
#define HID    64
#define BLK    512

constexpr float DTf = 1.0f / 128.0f;
constexpr float TWO_LOG2E = 2.88539008177792681f;

typedef float v2f __attribute__((ext_vector_type(2)));

__device__ __forceinline__ v2f v2ld(const float* p) { return *(const v2f*)p; }
__device__ __forceinline__ v2f bc(float s) { v2f r = {s, s}; return r; }
// elementwise fma on pairs -> llvm.fma.v2f32 -> V_PK_FMA_F32 (gfx90a+)
__device__ __forceinline__ v2f pkfma(v2f a, v2f b, v2f c) {
    return __builtin_elementwise_fma(a, b, c);
}

struct CD { float c, dre, dim; };

// scalar tanh via hw exp2 + rcp (saturates exactly)
__device__ __forceinline__ float fast_tanh(float x) {
    float e = __builtin_amdgcn_exp2f(x * TWO_LOG2E);
    return 1.0f - 2.0f * __builtin_amdgcn_rcpf(e + 1.0f);
}
// packed-pair tanh: pk VALU + per-component exp2/rcp
__device__ __forceinline__ v2f fast_tanh2(v2f z) {
    v2f zs = z * TWO_LOG2E;
    v2f e;
    e.x = __builtin_amdgcn_exp2f(zs.x);
    e.y = __builtin_amdgcn_exp2f(zs.y);
    v2f e1 = e + 1.0f;
    v2f r;
    r.x = __builtin_amdgcn_rcpf(e1.x);
    r.y = __builtin_amdgcn_rcpf(e1.y);
    return pkfma(bc(-2.0f), r, bc(1.0f));
}

// ---- grad MLP: 5 -> 64 -> 6, packed pairs ----
__device__ __forceinline__ void grad_mlp(
    float n, float x0, float x1, float x2, float p,
    const float* __restrict__ w1, const float* __restrict__ b1,
    const float* __restrict__ w2, const float* __restrict__ b2,
    float& og0, float& og1, float& og2, float& og3, float& og4, float& og5)
{
    v2f og01 = { b2[0], b2[1] };
    v2f og23 = { b2[2], b2[3] };
    v2f og45 = { b2[4], b2[5] };
#pragma unroll 4
    for (int j = 0; j < HID; j += 2) {
        v2f z = pkfma(bc(n),  v2ld(w1 + j),
                pkfma(bc(x0), v2ld(w1 + HID   + j),
                pkfma(bc(x1), v2ld(w1 + 2*HID + j),
                pkfma(bc(x2), v2ld(w1 + 3*HID + j),
                pkfma(bc(p),  v2ld(w1 + 4*HID + j), v2ld(b1 + j))))));
        v2f h = fast_tanh2(z);
        const float* wj = w2 + j*6;
        og01 = pkfma(bc(h.x), v2ld(wj),     pkfma(bc(h.y), v2ld(wj + 6),  og01));
        og23 = pkfma(bc(h.x), v2ld(wj + 2), pkfma(bc(h.y), v2ld(wj + 8),  og23));
        og45 = pkfma(bc(h.x), v2ld(wj + 4), pkfma(bc(h.y), v2ld(wj + 10), og45));
    }
    og0 = og01.x; og1 = og01.y; og2 = og23.x;
    og3 = og23.y; og4 = og45.x; og5 = og45.y;
}

// ---- jump MLP, double-sided (3-op identity form) ----
template<bool USE_TD>
__device__ __forceinline__ void jump_mlp(
    float n, float x0, float x1, float x2, float p,
    const float* __restrict__ v1, const float* __restrict__ c1,
    const float* __restrict__ vw2, const float* __restrict__ Td,
    float& dup0, float& dup1, float& dum0, float& dum1)
{
    v2f dup01 = { 0.f, 0.f };
    v2f dum01 = { 0.f, 0.f };
#pragma unroll 4
    for (int j = 0; j < HID; j += 2) {
        v2f d  = v2ld(v1 + j);
        v2f zb = pkfma(bc(n), d,
                 pkfma(bc(x0), v2ld(v1 + HID   + j),
                 pkfma(bc(x1), v2ld(v1 + 2*HID + j),
                 pkfma(bc(x2), v2ld(v1 + 3*HID + j),
                 pkfma(bc(p),  v2ld(v1 + 4*HID + j), v2ld(c1 + j))))));
        v2f T  = fast_tanh2(zb);
        v2f Tv;
        if (USE_TD) Tv = v2ld(Td + j);
        else { Tv.x = fast_tanh(d.x); Tv.y = fast_tanh(d.y); }
        v2f a    = T * Tv;
        v2f oma2 = pkfma(-a, a, bc(1.0f));
        v2f r;
        r.x = __builtin_amdgcn_rcpf(oma2.x);
        r.y = __builtin_amdgcn_rcpf(oma2.y);
        v2f s1 = (T + Tv) * r;
        v2f u1 = s1 - T;
        v2f ep = pkfma(-s1, a, u1);         // (T+Tv)(1-a)r - T
        v2f s2 = (T - Tv) * r;
        v2f u2 = s2 - T;
        v2f em = pkfma(s2, a, u2);          // (T-Tv)(1+a)r - T
        v2f wv0 = v2ld(vw2 + 2*j);
        v2f wv1 = v2ld(vw2 + 2*j + 2);
        dup01 = pkfma(bc(ep.x), wv0, pkfma(bc(ep.y), wv1, dup01));
        dum01 = pkfma(bc(em.x), wv0, pkfma(bc(em.y), wv1, dum01));
    }
    dup0 = dup01.x; dup1 = dup01.y;
    dum0 = dum01.x; dum1 = dum01.y;
}

// ---- jump MLP, single-sided: e = tanh(zb + sgn*d) - tanh(zb), sgn = dN = +-1 ----
__device__ __forceinline__ void jump_mlp_1s(
    float n, float x0, float x1, float x2, float p, float sgn,
    const float* __restrict__ v1, const float* __restrict__ c1,
    const float* __restrict__ vw2, const float* __restrict__ Td,
    float& e0, float& e1)
{
    v2f acc = { 0.f, 0.f };
#pragma unroll 4
    for (int j = 0; j < HID; j += 2) {
        v2f d  = v2ld(v1 + j);
        v2f zb = pkfma(bc(n), d,
                 pkfma(bc(x0), v2ld(v1 + HID   + j),
                 pkfma(bc(x1), v2ld(v1 + 2*HID + j),
                 pkfma(bc(x2), v2ld(v1 + 3*HID + j),
                 pkfma(bc(p),  v2ld(v1 + 4*HID + j), v2ld(c1 + j))))));
        v2f T   = fast_tanh2(zb);
        v2f Tsv = bc(sgn) * v2ld(Td + j);   // tanh(sgn*d) = sgn*tanh(d)
        v2f as  = T * Tsv;
        v2f oma = pkfma(-as, as, bc(1.0f));
        v2f r;
        r.x = __builtin_amdgcn_rcpf(oma.x);
        r.y = __builtin_amdgcn_rcpf(oma.y);
        v2f s1 = (T + Tsv) * r;
        v2f u1 = s1 - T;
        v2f e  = pkfma(-s1, as, u1);        // (T+Tsv)(1-as)r - T
        acc = pkfma(bc(e.x), v2ld(vw2 + 2*j), pkfma(bc(e.y), v2ld(vw2 + 2*j + 2), acc));
    }
    e0 = acc.x; e1 = acc.y;
}

// Full step (fallback path)
template<bool USE_TD>
__device__ __forceinline__ CD step_core(
    float n, float x0, float x1, float x2, float p, float t,
    float db0, float db1, float db2, float dN, float phi,
    const float* __restrict__ w1, const float* __restrict__ b1,
    const float* __restrict__ w2, const float* __restrict__ b2,
    const float* __restrict__ v1, const float* __restrict__ c1,
    const float* __restrict__ vw2, const float* __restrict__ Td)
{
    float og0, og1, og2, og3, og4, og5;
    grad_mlp(n,x0,x1,x2,p, w1,b1,w2,b2, og0,og1,og2,og3,og4,og5);
    float dup0, dup1, dum0, dum1;
    jump_mlp<USE_TD>(n,x0,x1,x2,p, v1,c1,vw2,Td, dup0,dup1,dum0,dum1);

    float r2    = fmaf(x0,x0, fmaf(x1,x1, x2*x2));
    float gamma = 0.1f - (0.5f + 0.1f*r2) * __builtin_amdgcn_rcpf(1.0f + r2);
    float xdb   = fmaf(x0,db0, fmaf(x1,db1, x2*db2));
    float kc    = sqrtf(fmaf(0.2f, fabsf(n), 1.0f));
    float gdb_r = fmaf(og0,db0, fmaf(og1,db1, og2*db2));
    float gdb_i = fmaf(og3,db0, fmaf(og4,db1, og5*db2));
    float gx_r  = fmaf(og0,x0,  fmaf(og1,x1,  og2*x2));
    float gx_i  = fmaf(og3,x0,  fmaf(og4,x1,  og5*x2));
    float gb_r  = kc * fmaf(gamma*xdb, gx_r, 0.5f*gdb_r);
    float gb_i  = kc * fmaf(gamma*xdb, gx_i, 0.5f*gdb_i);

    float alpha = 0.5f*(n + 1.0f);
    float beta  = fmaf(0.4f, fabsf(n), 0.1f);
    float cf    = 0.1f*(1.0f + t)*DTf;
    float d0r = gb_r - (alpha*dup0 + beta*dum0)*DTf - cf*(og0+og1+og2);
    float d0i = gb_i - (alpha*dup1 + beta*dum1)*DTf - cf*(og3+og4+og5);

    float c, sr, si;
    if (dN > 0.5f)       { c = 1.0f;          sr = dup0; si = dup1; }
    else if (dN < -0.5f) { c = 1.0f;          sr = dum0; si = dum1; }
    else                 { c = 1.0f - p*DTf;  sr = d0r;  si = d0i;  }

    float sp, cp;
    __sincosf(phi, &sp, &cp);
    CD o;
    o.c   = c;
    o.dre = fmaf(cp, sr,  sp*si);
    o.dim = fmaf(cp, si, -sp*sr);
    return o;
}

__device__ __forceinline__ void mlp_u0(
    float n, float x0, float x1, float x2, float p,
    const float* __restrict__ w1, const float* __restrict__ b1,
    const float* __restrict__ w2, const float* __restrict__ b2,
    float& ur, float& ui)
{
    v2f o01 = { b2[0], b2[1] };
#pragma unroll 4
    for (int j = 0; j < HID; j += 2) {
        v2f z = pkfma(bc(n),  v2ld(w1 + j),
                pkfma(bc(x0), v2ld(w1 + HID   + j),
                pkfma(bc(x1), v2ld(w1 + 2*HID + j),
                pkfma(bc(x2), v2ld(w1 + 3*HID + j),
                pkfma(bc(p),  v2ld(w1 + 4*HID + j), v2ld(b1 + j))))));
        v2f h = fast_tanh2(z);
        o01 = pkfma(bc(h.x), v2ld(w2 + 2*j), pkfma(bc(h.y), v2ld(w2 + 2*j + 2), o01));
    }
    ur = o01.x; ui = o01.y;
}

// ---- Pass 1: phi prefix ----
__global__ void __launch_bounds__(256) k_phi(
    const float* __restrict__ X, const float* __restrict__ P,
    float* __restrict__ phi, float* __restrict__ phiF)
{
    int b = blockIdx.x*256 + threadIdx.x;
    double s = 0.0;
    for (int k = 0; k < NSTEPS; k++) {
        size_t idx = (size_t)k*BATCH + b;
        phi[idx] = (float)(DTf * s);
        float p = P[idx];
        const float* xp = X + idx*3;
        float x0 = xp[0], x1 = xp[1], x2 = xp[2];
        s += (double)p * (double)(x0*x0 + x1*x1 + x2*x2);
    }
    phiF[b] = (float)(DTf * s);
}

// ---- Pass 2: compacted, class-specialized per-wave ----
__global__ void __launch_bounds__(BLK) k_step(
    const float* __restrict__ N,  const float* __restrict__ X,
    const float* __restrict__ P,  const float* __restrict__ Tarr,
    const float* __restrict__ dB,
    const float* __restrict__ Wg1, const float* __restrict__ bg1,
    const float* __restrict__ Wg2, const float* __restrict__ bg2,
    const float* __restrict__ Wj1, const float* __restrict__ bj1,
    const float* __restrict__ Wj2, const float* __restrict__ bj2,
    const float* __restrict__ phiA, float* __restrict__ cA, float2* __restrict__ dA)
{
    int k = blockIdx.y;
    const float* w1  = Wg1 + k*5*HID;
    const float* b1  = bg1 + k*HID;
    const float* w2  = Wg2 + k*HID*6;
    const float* b2  = bg2 + k*6;
    const float* v1  = Wj1 + k*5*HID;
    const float* c1  = bj1 + k*HID;
    const float* vw2 = Wj2 + k*HID*2;
    float t = Tarr[k];

    __shared__ float Td[HID];
    __shared__ float sdat[BLK][13];             // stride 13: conflict-benign
    __shared__ int   sorig[BLK];
    __shared__ int   cnt[2];
    if (threadIdx.x < HID) Td[threadIdx.x] = fast_tanh(v1[threadIdx.x]);
    if (threadIdx.x == 0) { cnt[0] = 0; cnt[1] = 0; }
    __syncthreads();

    int tid = threadIdx.x;
    int b = blockIdx.x*BLK + tid;
    size_t idx = (size_t)k*BATCH + b;
    {
        float n  = N[idx], p = P[idx];
        const float* xp  = X  + idx*3;
        const float* dbp = dB + idx*3;
        float dN = N[idx + BATCH] - n;          // exact +-1/0 in fp32
        bool full = (dN == 0.0f);
        int pos = full ? atomicAdd(&cnt[0], 1) : (BLK-1) - atomicAdd(&cnt[1], 1);
        sorig[pos]  = b;
        float* sd = sdat[pos];
        sd[0]=n;      sd[1]=p;      sd[2]=xp[0]; sd[3]=xp[1]; sd[4]=xp[2];
        sd[5]=dbp[0]; sd[6]=dbp[1]; sd[7]=dbp[2];
        sd[8]=phiA[idx]; sd[9]=dN;
    }
    __syncthreads();

    const float* md = sdat[tid];
    float n   = md[0], p   = md[1];
    float x0  = md[2], x1  = md[3], x2 = md[4];
    float db0 = md[5], db1 = md[6], db2 = md[7];
    float phi = md[8], dN  = md[9];
    int   ob  = sorig[tid];
    bool  g   = (dN == 0.0f);

    float c, sr, si;
    if (__ballot(g) != 0ull) {
        // ---- full / mixed wave ----
        float dup0, dup1, dum0, dum1;
        jump_mlp<true>(n,x0,x1,x2,p, v1,c1,vw2,Td, dup0,dup1,dum0,dum1);
        float og0, og1, og2, og3, og4, og5;
        grad_mlp(n,x0,x1,x2,p, w1,b1,w2,b2, og0,og1,og2,og3,og4,og5);

        float r2    = fmaf(x0,x0, fmaf(x1,x1, x2*x2));
        float gamma = 0.1f - (0.5f + 0.1f*r2) * __builtin_amdgcn_rcpf(1.0f + r2);
        float xdb   = fmaf(x0,db0, fmaf(x1,db1, x2*db2));
        float kc    = sqrtf(fmaf(0.2f, fabsf(n), 1.0f));
        float gdb_r = fmaf(og0,db0, fmaf(og1,db1, og2*db2));
        float gdb_i = fmaf(og3,db0, fmaf(og4,db1, og5*db2));
        float gx_r  = fmaf(og0,x0,  fmaf(og1,x1,  og2*x2));
        float gx_i  = fmaf(og3,x0,  fmaf(og4,x1,  og5*x2));
        float gb_r  = kc * fmaf(gamma*xdb, gx_r, 0.5f*gdb_r);
        float gb_i  = kc * fmaf(gamma*xdb, gx_i, 0.5f*gdb_i);

        float alpha = 0.5f*(n + 1.0f);
        float beta  = fmaf(0.4f, fabsf(n), 0.1f);
        float cf    = 0.1f*(1.0f + t)*DTf;
        float d0r = gb_r - (alpha*dup0 + beta*dum0)*DTf - cf*(og0+og1+og2);
        float d0i = gb_i - (alpha*dup1 + beta*dum1)*DTf - cf*(og3+og4+og5);

        if (dN > 0.5f)       { c = 1.0f;          sr = dup0; si = dup1; }
        else if (dN < -0.5f) { c = 1.0f;          sr = dum0; si = dum1; }
        else                 { c = 1.0f - p*DTf;  sr = d0r;  si = d0i;  }
    } else {
        // ---- pure jump wave: single-sided, no grad ----
        jump_mlp_1s(n,x0,x1,x2,p, dN, v1,c1,vw2,Td, sr, si);
        c = 1.0f;
    }

    float sp, cp;
    __sincosf(phi, &sp, &cp);
    size_t oidx = (size_t)k*BATCH + ob;
    cA[oidx] = c;
    dA[oidx] = make_float2(fmaf(cp, sr,  sp*si), fmaf(cp, si, -sp*sr));
}

// ---- Pass 3: u0 MLP + affine fold + g ----
__global__ void __launch_bounds__(256) k_combine(
    const float* __restrict__ N, const float* __restrict__ X, const float* __restrict__ P,
    const float* __restrict__ Wr1, const float* __restrict__ br1,
    const float* __restrict__ Wr2, const float* __restrict__ br2,
    const float* __restrict__ cA, const float2* __restrict__ dA,
    const float* __restrict__ phiF, float* __restrict__ out, int full)
{
    int b = blockIdx.x*256 + threadIdx.x;
    const float* xp = X + (size_t)b*3;
    float ur, ui;
    mlp_u0(N[b], xp[0], xp[1], xp[2], P[b], Wr1, br1, Wr2, br2, ur, ui);
#pragma unroll 8
    for (int k = 0; k < NSTEPS; k++) {
        size_t idx = (size_t)k*BATCH + b;
        float  c = cA[idx];
        float2 d = dA[idx];
        ur = fmaf(c, ur, d.x);
        ui = fmaf(c, ui, d.y);
    }
    float phi = phiF[b];
    const float* xf = X + ((size_t)NSTEPS*BATCH + b)*3;
    float s = xf[0] + xf[1] + xf[2];
    float sp, cp;
    __sincosf(phi, &sp, &cp);
    float gre =  s*cp;
    float gim = -s*sp;
    if (full) {
        out[b]           = ur;
        out[BATCH + b]   = ui;
        out[2*BATCH + b] = gre;
        out[3*BATCH + b] = gim;
    } else {
        out[b]         = ur;
        out[BATCH + b] = gre;
    }
}

// ---- Fallback (no workspace) ----
__global__ void __launch_bounds__(256) k_fused(
    const float* __restrict__ N,  const float* __restrict__ X,
    const float* __restrict__ P,  const float* __restrict__ Tarr,
    const float* __restrict__ dB,
    const float* __restrict__ Wr1, const float* __restrict__ br1,
    const float* __restrict__ Wr2, const float* __restrict__ br2,
    const float* __restrict__ Wg1, const float* __restrict__ bg1,
    const float* __restrict__ Wg2, const float* __restrict__ bg2,
    const float* __restrict__ Wj1, const float* __restrict__ bj1,
    const float* __restrict__ Wj2, const float* __restrict__ bj2,
    float* __restrict__ out, int full)
{
    int b = blockIdx.x*256 + threadIdx.x;
    float ur, ui;
    {
        const float* xp = X + (size_t)b*3;
        mlp_u0(N[b], xp[0], xp[1], xp[2], P[b], Wr1, br1, Wr2, br2, ur, ui);
    }
    double s = 0.0;
    for (int k = 0; k < NSTEPS; k++) {
        size_t idx = (size_t)k*BATCH + b;
        float n = N[idx], p = P[idx], t = Tarr[k];
        const float* xp  = X  + idx*3;
        const float* dbp = dB + idx*3;
        float dN  = N[idx + BATCH] - n;
        float phi = (float)(DTf * s);
        CD cd = step_core<false>(n, xp[0], xp[1], xp[2], p, t,
                                 dbp[0], dbp[1], dbp[2], dN, phi,
                                 Wg1 + k*5*HID, bg1 + k*HID,
                                 Wg2 + k*HID*6, bg2 + k*6,
                                 Wj1 + k*5*HID, bj1 + k*HID,
                                 Wj2 + k*HID*2, nullptr);
        ur = fmaf(cd.c, ur, cd.dre);
        ui = fmaf(cd.c, ui, cd.dim);
        float x0 = xp[0], x1 = xp[1], x2 = xp[2];
        s += (double)p * (double)(x0*x0 + x1*x1 + x2*x2);
    }
    float phi = (float)(DTf * s);
    const float* xf = X + ((size_t)NSTEPS*BATCH + b)*3;
    float sm = xf[0] + xf[1] + xf[2];
    float sp, cp;
    __sincosf(phi, &sp, &cp);
    float gre =  sm*cp;
    float gim = -sm*sp;
    if (full) {
        out[b]           = ur;
        out[BATCH + b]   = ui;
        out[2*BATCH + b] = gre;
        out[3*BATCH + b] = gim;
    } else {
        out[b]         = ur;
        out[BATCH + b] = gre;
    }
}

extern "C" void kernel_launch(void* const* d_in, const int* in_sizes, int n_in,
                              void* d_out, int out_size, void* d_ws, size_t ws_size,
                              hipStream_t stream)
{
    const float* N    = (const float*)d_in[0];
    const float* X    = (const float*)d_in[1];
    const float* P    = (const float*)d_in[2];
    const float* Tarr = (const float*)d_in[3];
    const float* dB   = (const float*)d_in[4];
    const float* Wr1  = (const float*)d_in[5];
    const float* br1  = (const float*)d_in[6];
    const float* Wr2  = (const float*)d_in[7];
    const float* br2  = (const float*)d_in[8];
    const float* Wg1  = (const float*)d_in[9];
    const float* bg1  = (const float*)d_in[10];
    const float* Wg2  = (const float*)d_in[11];
    const float* bg2  = (const float*)d_in[12];
    const float* Wj1  = (const float*)d_in[13];
    const float* bj1  = (const float*)d_in[14];
    const float* Wj2  = (const float*)d_in[15];
    const float* bj2  = (const float*)d_in[16];
    float* out = (float*)d_out;

    const int full = (out_size >= 4*BATCH) ? 1 : 0;

    const size_t phi_elems = (size_t)NSTEPS*BATCH;
    const size_t need = (phi_elems + BATCH + phi_elems)*sizeof(float)
                      + phi_elems*sizeof(float2);

    if (ws_size >= need) {
        float*  phiA = (float*)d_ws;
        float*  phiF = phiA + phi_elems;
        float*  cA   = phiF + BATCH;
        float2* dA   = (float2*)(cA + phi_elems);

        k_phi<<<dim3(BATCH/256), dim3(256), 0, stream>>>(X, P, phiA, phiF);
        k_step<<<dim3(BATCH/BLK, NSTEPS), dim3(BLK), 0, stream>>>(
            N, X, P, Tarr, dB, Wg1, bg1, Wg2, bg2, Wj1, bj1, Wj2, bj2,
            phiA, cA, dA);
        k_combine<<<dim3(BATCH/256), dim3(256), 0, stream>>>(
            N, X, P, Wr1, br1, Wr2, br2, cA, dA, phiF, out, full);
    } else {
        k_fused<<<dim3(BATCH/256), dim3(256), 0, stream>>>(
            N, X, P, Tarr, dB, Wr1, br1, Wr2, br2,
            Wg1, bg1, Wg2, bg2, Wj1, bj1, Wj2, bj2, out, full);
    }
}

// Round 15
// 215.278 us; speedup vs baseline: 2.0713x; 1.0124x over previous
//
#include <hip/hip_runtime.h>
#include <math.h>

#define NSTEPS 128
#define BATCH  32768
#define HID    64
#define BLK    512

constexpr float DTf = 1.0f / 128.0f;
constexpr float TWO_LOG2E = 2.88539008177792681f;

typedef float v2f __attribute__((ext_vector_type(2)));

__device__ __forceinline__ v2f v2ld(const float* p) { return *(const v2f*)p; }
__device__ __forceinline__ v2f bc(float s) { v2f r = {s, s}; return r; }
__device__ __forceinline__ v2f pkfma(v2f a, v2f b, v2f c) {
    return __builtin_elementwise_fma(a, b, c);
}

struct CD { float c, dre, dim; };

// scalar tanh via hw exp2 + rcp (saturates exactly)
__device__ __forceinline__ float fast_tanh(float x) {
    float e = __builtin_amdgcn_exp2f(x * TWO_LOG2E);
    return 1.0f - 2.0f * __builtin_amdgcn_rcpf(e + 1.0f);
}
// packed-pair tanh: pk VALU + per-component exp2/rcp
__device__ __forceinline__ v2f fast_tanh2(v2f z) {
    v2f zs = z * TWO_LOG2E;
    v2f e;
    e.x = __builtin_amdgcn_exp2f(zs.x);
    e.y = __builtin_amdgcn_exp2f(zs.y);
    v2f e1 = e + 1.0f;
    v2f r;
    r.x = __builtin_amdgcn_rcpf(e1.x);
    r.y = __builtin_amdgcn_rcpf(e1.y);
    return pkfma(bc(-2.0f), r, bc(1.0f));
}

// ---- grad MLP: 5 -> 64 -> 6, packed pairs ----
__device__ __forceinline__ void grad_mlp(
    float n, float x0, float x1, float x2, float p,
    const float* __restrict__ w1, const float* __restrict__ b1,
    const float* __restrict__ w2, const float* __restrict__ b2,
    float& og0, float& og1, float& og2, float& og3, float& og4, float& og5)
{
    v2f og01 = { b2[0], b2[1] };
    v2f og23 = { b2[2], b2[3] };
    v2f og45 = { b2[4], b2[5] };
#pragma unroll 4
    for (int j = 0; j < HID; j += 2) {
        v2f z = pkfma(bc(n),  v2ld(w1 + j),
                pkfma(bc(x0), v2ld(w1 + HID   + j),
                pkfma(bc(x1), v2ld(w1 + 2*HID + j),
                pkfma(bc(x2), v2ld(w1 + 3*HID + j),
                pkfma(bc(p),  v2ld(w1 + 4*HID + j), v2ld(b1 + j))))));
        v2f h = fast_tanh2(z);
        const float* wj = w2 + j*6;
        og01 = pkfma(bc(h.x), v2ld(wj),     pkfma(bc(h.y), v2ld(wj + 6),  og01));
        og23 = pkfma(bc(h.x), v2ld(wj + 2), pkfma(bc(h.y), v2ld(wj + 8),  og23));
        og45 = pkfma(bc(h.x), v2ld(wj + 4), pkfma(bc(h.y), v2ld(wj + 10), og45));
    }
    og0 = og01.x; og1 = og01.y; og2 = og23.x;
    og3 = og23.y; og4 = og45.x; og5 = og45.y;
}

// ---- jump MLP, double-sided (3-op identity form) ----
template<bool USE_TD>
__device__ __forceinline__ void jump_mlp(
    float n, float x0, float x1, float x2, float p,
    const float* __restrict__ v1, const float* __restrict__ c1,
    const float* __restrict__ vw2, const float* __restrict__ Td,
    float& dup0, float& dup1, float& dum0, float& dum1)
{
    v2f dup01 = { 0.f, 0.f };
    v2f dum01 = { 0.f, 0.f };
#pragma unroll 4
    for (int j = 0; j < HID; j += 2) {
        v2f d  = v2ld(v1 + j);
        v2f zb = pkfma(bc(n), d,
                 pkfma(bc(x0), v2ld(v1 + HID   + j),
                 pkfma(bc(x1), v2ld(v1 + 2*HID + j),
                 pkfma(bc(x2), v2ld(v1 + 3*HID + j),
                 pkfma(bc(p),  v2ld(v1 + 4*HID + j), v2ld(c1 + j))))));
        v2f T  = fast_tanh2(zb);
        v2f Tv;
        if (USE_TD) Tv = v2ld(Td + j);
        else { Tv.x = fast_tanh(d.x); Tv.y = fast_tanh(d.y); }
        v2f a    = T * Tv;
        v2f oma2 = pkfma(-a, a, bc(1.0f));
        v2f r;
        r.x = __builtin_amdgcn_rcpf(oma2.x);
        r.y = __builtin_amdgcn_rcpf(oma2.y);
        v2f s1 = (T + Tv) * r;
        v2f u1 = s1 - T;
        v2f ep = pkfma(-s1, a, u1);         // (T+Tv)(1-a)r - T
        v2f s2 = (T - Tv) * r;
        v2f u2 = s2 - T;
        v2f em = pkfma(s2, a, u2);          // (T-Tv)(1+a)r - T
        v2f wv0 = v2ld(vw2 + 2*j);
        v2f wv1 = v2ld(vw2 + 2*j + 2);
        dup01 = pkfma(bc(ep.x), wv0, pkfma(bc(ep.y), wv1, dup01));
        dum01 = pkfma(bc(em.x), wv0, pkfma(bc(em.y), wv1, dum01));
    }
    dup0 = dup01.x; dup1 = dup01.y;
    dum0 = dum01.x; dum1 = dum01.y;
}

// ---- jump MLP, single-sided: e = tanh(zb + sgn*d) - tanh(zb), sgn = dN = +-1 ----
__device__ __forceinline__ void jump_mlp_1s(
    float n, float x0, float x1, float x2, float p, float sgn,
    const float* __restrict__ v1, const float* __restrict__ c1,
    const float* __restrict__ vw2, const float* __restrict__ Td,
    float& e0, float& e1)
{
    v2f acc = { 0.f, 0.f };
#pragma unroll 4
    for (int j = 0; j < HID; j += 2) {
        v2f d  = v2ld(v1 + j);
        v2f zb = pkfma(bc(n), d,
                 pkfma(bc(x0), v2ld(v1 + HID   + j),
                 pkfma(bc(x1), v2ld(v1 + 2*HID + j),
                 pkfma(bc(x2), v2ld(v1 + 3*HID + j),
                 pkfma(bc(p),  v2ld(v1 + 4*HID + j), v2ld(c1 + j))))));
        v2f T   = fast_tanh2(zb);
        v2f Tsv = bc(sgn) * v2ld(Td + j);   // tanh(sgn*d) = sgn*tanh(d)
        v2f as  = T * Tsv;
        v2f oma = pkfma(-as, as, bc(1.0f));
        v2f r;
        r.x = __builtin_amdgcn_rcpf(oma.x);
        r.y = __builtin_amdgcn_rcpf(oma.y);
        v2f s1 = (T + Tsv) * r;
        v2f u1 = s1 - T;
        v2f e  = pkfma(-s1, as, u1);        // (T+Tsv)(1-as)r - T
        acc = pkfma(bc(e.x), v2ld(vw2 + 2*j), pkfma(bc(e.y), v2ld(vw2 + 2*j + 2), acc));
    }
    e0 = acc.x; e1 = acc.y;
}

// Full step (fallback path)
template<bool USE_TD>
__device__ __forceinline__ CD step_core(
    float n, float x0, float x1, float x2, float p, float t,
    float db0, float db1, float db2, float dN, float phi,
    const float* __restrict__ w1, const float* __restrict__ b1,
    const float* __restrict__ w2, const float* __restrict__ b2,
    const float* __restrict__ v1, const float* __restrict__ c1,
    const float* __restrict__ vw2, const float* __restrict__ Td)
{
    float og0, og1, og2, og3, og4, og5;
    grad_mlp(n,x0,x1,x2,p, w1,b1,w2,b2, og0,og1,og2,og3,og4,og5);
    float dup0, dup1, dum0, dum1;
    jump_mlp<USE_TD>(n,x0,x1,x2,p, v1,c1,vw2,Td, dup0,dup1,dum0,dum1);

    float r2    = fmaf(x0,x0, fmaf(x1,x1, x2*x2));
    float gamma = 0.1f - (0.5f + 0.1f*r2) * __builtin_amdgcn_rcpf(1.0f + r2);
    float xdb   = fmaf(x0,db0, fmaf(x1,db1, x2*db2));
    float kc    = sqrtf(fmaf(0.2f, fabsf(n), 1.0f));
    float gdb_r = fmaf(og0,db0, fmaf(og1,db1, og2*db2));
    float gdb_i = fmaf(og3,db0, fmaf(og4,db1, og5*db2));
    float gx_r  = fmaf(og0,x0,  fmaf(og1,x1,  og2*x2));
    float gx_i  = fmaf(og3,x0,  fmaf(og4,x1,  og5*x2));
    float gb_r  = kc * fmaf(gamma*xdb, gx_r, 0.5f*gdb_r);
    float gb_i  = kc * fmaf(gamma*xdb, gx_i, 0.5f*gdb_i);

    float alpha = 0.5f*(n + 1.0f);
    float beta  = fmaf(0.4f, fabsf(n), 0.1f);
    float cf    = 0.1f*(1.0f + t)*DTf;
    float d0r = gb_r - (alpha*dup0 + beta*dum0)*DTf - cf*(og0+og1+og2);
    float d0i = gb_i - (alpha*dup1 + beta*dum1)*DTf - cf*(og3+og4+og5);

    float c, sr, si;
    if (dN > 0.5f)       { c = 1.0f;          sr = dup0; si = dup1; }
    else if (dN < -0.5f) { c = 1.0f;          sr = dum0; si = dum1; }
    else                 { c = 1.0f - p*DTf;  sr = d0r;  si = d0i;  }

    float sp, cp;
    __sincosf(phi, &sp, &cp);
    CD o;
    o.c   = c;
    o.dre = fmaf(cp, sr,  sp*si);
    o.dim = fmaf(cp, si, -sp*sr);
    return o;
}

__device__ __forceinline__ void mlp_u0(
    float n, float x0, float x1, float x2, float p,
    const float* __restrict__ w1, const float* __restrict__ b1,
    const float* __restrict__ w2, const float* __restrict__ b2,
    float& ur, float& ui)
{
    v2f o01 = { b2[0], b2[1] };
#pragma unroll 4
    for (int j = 0; j < HID; j += 2) {
        v2f z = pkfma(bc(n),  v2ld(w1 + j),
                pkfma(bc(x0), v2ld(w1 + HID   + j),
                pkfma(bc(x1), v2ld(w1 + 2*HID + j),
                pkfma(bc(x2), v2ld(w1 + 3*HID + j),
                pkfma(bc(p),  v2ld(w1 + 4*HID + j), v2ld(b1 + j))))));
        v2f h = fast_tanh2(z);
        o01 = pkfma(bc(h.x), v2ld(w2 + 2*j), pkfma(bc(h.y), v2ld(w2 + 2*j + 2), o01));
    }
    ur = o01.x; ui = o01.y;
}

// ---- Pass 1: phi prefix ----
__global__ void __launch_bounds__(256) k_phi(
    const float* __restrict__ X, const float* __restrict__ P,
    float* __restrict__ phi, float* __restrict__ phiF)
{
    int b = blockIdx.x*256 + threadIdx.x;
    double s = 0.0;
    for (int k = 0; k < NSTEPS; k++) {
        size_t idx = (size_t)k*BATCH + b;
        phi[idx] = (float)(DTf * s);
        float p = P[idx];
        const float* xp = X + idx*3;
        float x0 = xp[0], x1 = xp[1], x2 = xp[2];
        s += (double)p * (double)(x0*x0 + x1*x1 + x2*x2);
    }
    phiF[b] = (float)(DTf * s);
}

// ---- Pass 2: compaction by INDEX PERMUTATION only (LDS ~2.3KB -> full occupancy).
// Rank tasks (full first) via LDS atomics, then each thread re-reads its
// assigned task's inputs from global (within-block window -> L1/L2-hot).
// Atomic order is nondeterministic but results are keyed by original index
// -> output deterministic.
__global__ void __launch_bounds__(BLK) k_step(
    const float* __restrict__ N,  const float* __restrict__ X,
    const float* __restrict__ P,  const float* __restrict__ Tarr,
    const float* __restrict__ dB,
    const float* __restrict__ Wg1, const float* __restrict__ bg1,
    const float* __restrict__ Wg2, const float* __restrict__ bg2,
    const float* __restrict__ Wj1, const float* __restrict__ bj1,
    const float* __restrict__ Wj2, const float* __restrict__ bj2,
    const float* __restrict__ phiA, float* __restrict__ cA, float2* __restrict__ dA)
{
    int k = blockIdx.y;
    const float* w1  = Wg1 + k*5*HID;
    const float* b1  = bg1 + k*HID;
    const float* w2  = Wg2 + k*HID*6;
    const float* b2  = bg2 + k*6;
    const float* v1  = Wj1 + k*5*HID;
    const float* c1  = bj1 + k*HID;
    const float* vw2 = Wj2 + k*HID*2;
    float t = Tarr[k];

    __shared__ float Td[HID];
    __shared__ unsigned short sorig[BLK];
    __shared__ int cnt[2];
    if (threadIdx.x < HID) Td[threadIdx.x] = fast_tanh(v1[threadIdx.x]);
    if (threadIdx.x == 0) { cnt[0] = 0; cnt[1] = 0; }
    __syncthreads();

    int tid  = threadIdx.x;
    int base = blockIdx.x*BLK;
    {
        size_t i0 = (size_t)k*BATCH + base + tid;
        float n0  = N[i0];
        float dN0 = N[i0 + BATCH] - n0;       // exact +-1/0 in fp32
        bool full0 = (dN0 == 0.0f);
        int pos = full0 ? atomicAdd(&cnt[0], 1) : (BLK-1) - atomicAdd(&cnt[1], 1);
        sorig[pos] = (unsigned short)tid;
    }
    __syncthreads();

    int ob = base + sorig[tid];               // assigned (permuted) task
    size_t idx = (size_t)k*BATCH + ob;
    float n  = N[idx], p = P[idx];
    float dN = N[idx + BATCH] - n;
    const float* xp  = X  + idx*3;
    const float* dbp = dB + idx*3;
    float x0 = xp[0],  x1 = xp[1],  x2 = xp[2];
    float db0 = dbp[0], db1 = dbp[1], db2 = dbp[2];
    float phi = phiA[idx];
    bool  g   = (dN == 0.0f);

    float c, sr, si;
    if (__ballot(g) != 0ull) {
        // ---- full / mixed wave ----
        float dup0, dup1, dum0, dum1;
        jump_mlp<true>(n,x0,x1,x2,p, v1,c1,vw2,Td, dup0,dup1,dum0,dum1);
        float og0, og1, og2, og3, og4, og5;
        grad_mlp(n,x0,x1,x2,p, w1,b1,w2,b2, og0,og1,og2,og3,og4,og5);

        float r2    = fmaf(x0,x0, fmaf(x1,x1, x2*x2));
        float gamma = 0.1f - (0.5f + 0.1f*r2) * __builtin_amdgcn_rcpf(1.0f + r2);
        float xdb   = fmaf(x0,db0, fmaf(x1,db1, x2*db2));
        float kc    = sqrtf(fmaf(0.2f, fabsf(n), 1.0f));
        float gdb_r = fmaf(og0,db0, fmaf(og1,db1, og2*db2));
        float gdb_i = fmaf(og3,db0, fmaf(og4,db1, og5*db2));
        float gx_r  = fmaf(og0,x0,  fmaf(og1,x1,  og2*x2));
        float gx_i  = fmaf(og3,x0,  fmaf(og4,x1,  og5*x2));
        float gb_r  = kc * fmaf(gamma*xdb, gx_r, 0.5f*gdb_r);
        float gb_i  = kc * fmaf(gamma*xdb, gx_i, 0.5f*gdb_i);

        float alpha = 0.5f*(n + 1.0f);
        float beta  = fmaf(0.4f, fabsf(n), 0.1f);
        float cf    = 0.1f*(1.0f + t)*DTf;
        float d0r = gb_r - (alpha*dup0 + beta*dum0)*DTf - cf*(og0+og1+og2);
        float d0i = gb_i - (alpha*dup1 + beta*dum1)*DTf - cf*(og3+og4+og5);

        if (dN > 0.5f)       { c = 1.0f;          sr = dup0; si = dup1; }
        else if (dN < -0.5f) { c = 1.0f;          sr = dum0; si = dum1; }
        else                 { c = 1.0f - p*DTf;  sr = d0r;  si = d0i;  }
    } else {
        // ---- pure jump wave: single-sided, no grad ----
        jump_mlp_1s(n,x0,x1,x2,p, dN, v1,c1,vw2,Td, sr, si);
        c = 1.0f;
    }

    float sp, cp;
    __sincosf(phi, &sp, &cp);
    size_t oidx = (size_t)k*BATCH + ob;
    cA[oidx] = c;
    dA[oidx] = make_float2(fmaf(cp, sr,  sp*si), fmaf(cp, si, -sp*sr));
}

// ---- Pass 3: u0 MLP + affine fold + g ----
__global__ void __launch_bounds__(256) k_combine(
    const float* __restrict__ N, const float* __restrict__ X, const float* __restrict__ P,
    const float* __restrict__ Wr1, const float* __restrict__ br1,
    const float* __restrict__ Wr2, const float* __restrict__ br2,
    const float* __restrict__ cA, const float2* __restrict__ dA,
    const float* __restrict__ phiF, float* __restrict__ out, int full)
{
    int b = blockIdx.x*256 + threadIdx.x;
    const float* xp = X + (size_t)b*3;
    float ur, ui;
    mlp_u0(N[b], xp[0], xp[1], xp[2], P[b], Wr1, br1, Wr2, br2, ur, ui);
#pragma unroll 8
    for (int k = 0; k < NSTEPS; k++) {
        size_t idx = (size_t)k*BATCH + b;
        float  c = cA[idx];
        float2 d = dA[idx];
        ur = fmaf(c, ur, d.x);
        ui = fmaf(c, ui, d.y);
    }
    float phi = phiF[b];
    const float* xf = X + ((size_t)NSTEPS*BATCH + b)*3;
    float s = xf[0] + xf[1] + xf[2];
    float sp, cp;
    __sincosf(phi, &sp, &cp);
    float gre =  s*cp;
    float gim = -s*sp;
    if (full) {
        out[b]           = ur;
        out[BATCH + b]   = ui;
        out[2*BATCH + b] = gre;
        out[3*BATCH + b] = gim;
    } else {
        out[b]         = ur;
        out[BATCH + b] = gre;
    }
}

// ---- Fallback (no workspace) ----
__global__ void __launch_bounds__(256) k_fused(
    const float* __restrict__ N,  const float* __restrict__ X,
    const float* __restrict__ P,  const float* __restrict__ Tarr,
    const float* __restrict__ dB,
    const float* __restrict__ Wr1, const float* __restrict__ br1,
    const float* __restrict__ Wr2, const float* __restrict__ br2,
    const float* __restrict__ Wg1, const float* __restrict__ bg1,
    const float* __restrict__ Wg2, const float* __restrict__ bg2,
    const float* __restrict__ Wj1, const float* __restrict__ bj1,
    const float* __restrict__ Wj2, const float* __restrict__ bj2,
    float* __restrict__ out, int full)
{
    int b = blockIdx.x*256 + threadIdx.x;
    float ur, ui;
    {
        const float* xp = X + (size_t)b*3;
        mlp_u0(N[b], xp[0], xp[1], xp[2], P[b], Wr1, br1, Wr2, br2, ur, ui);
    }
    double s = 0.0;
    for (int k = 0; k < NSTEPS; k++) {
        size_t idx = (size_t)k*BATCH + b;
        float n = N[idx], p = P[idx], t = Tarr[k];
        const float* xp  = X  + idx*3;
        const float* dbp = dB + idx*3;
        float dN  = N[idx + BATCH] - n;
        float phi = (float)(DTf * s);
        CD cd = step_core<false>(n, xp[0], xp[1], xp[2], p, t,
                                 dbp[0], dbp[1], dbp[2], dN, phi,
                                 Wg1 + k*5*HID, bg1 + k*HID,
                                 Wg2 + k*HID*6, bg2 + k*6,
                                 Wj1 + k*5*HID, bj1 + k*HID,
                                 Wj2 + k*HID*2, nullptr);
        ur = fmaf(cd.c, ur, cd.dre);
        ui = fmaf(cd.c, ui, cd.dim);
        float x0 = xp[0], x1 = xp[1], x2 = xp[2];
        s += (double)p * (double)(x0*x0 + x1*x1 + x2*x2);
    }
    float phi = (float)(DTf * s);
    const float* xf = X + ((size_t)NSTEPS*BATCH + b)*3;
    float sm = xf[0] + xf[1] + xf[2];
    float sp, cp;
    __sincosf(phi, &sp, &cp);
    float gre =  sm*cp;
    float gim = -sm*sp;
    if (full) {
        out[b]           = ur;
        out[BATCH + b]   = ui;
        out[2*BATCH + b] = gre;
        out[3*BATCH + b] = gim;
    } else {
        out[b]         = ur;
        out[BATCH + b] = gre;
    }
}

extern "C" void kernel_launch(void* const* d_in, const int* in_sizes, int n_in,
                              void* d_out, int out_size, void* d_ws, size_t ws_size,
                              hipStream_t stream)
{
    const float* N    = (const float*)d_in[0];
    const float* X    = (const float*)d_in[1];
    const float* P    = (const float*)d_in[2];
    const float* Tarr = (const float*)d_in[3];
    const float* dB   = (const float*)d_in[4];
    const float* Wr1  = (const float*)d_in[5];
    const float* br1  = (const float*)d_in[6];
    const float* Wr2  = (const float*)d_in[7];
    const float* br2  = (const float*)d_in[8];
    const float* Wg1  = (const float*)d_in[9];
    const float* bg1  = (const float*)d_in[10];
    const float* Wg2  = (const float*)d_in[11];
    const float* bg2  = (const float*)d_in[12];
    const float* Wj1  = (const float*)d_in[13];
    const float* bj1  = (const float*)d_in[14];
    const float* Wj2  = (const float*)d_in[15];
    const float* bj2  = (const float*)d_in[16];
    float* out = (float*)d_out;

    const int full = (out_size >= 4*BATCH) ? 1 : 0;

    const size_t phi_elems = (size_t)NSTEPS*BATCH;
    const size_t need = (phi_elems + BATCH + phi_elems)*sizeof(float)
                      + phi_elems*sizeof(float2);

    if (ws_size >= need) {
        float*  phiA = (float*)d_ws;
        float*  phiF = phiA + phi_elems;
        float*  cA   = phiF + BATCH;
        float2* dA   = (float2*)(cA + phi_elems);

        k_phi<<<dim3(BATCH/256), dim3(256), 0, stream>>>(X, P, phiA, phiF);
        k_step<<<dim3(BATCH/BLK, NSTEPS), dim3(BLK), 0, stream>>>(
            N, X, P, Tarr, dB, Wg1, bg1, Wg2, bg2, Wj1, bj1, Wj2, bj2,
            phiA, cA, dA);
        k_combine<<<dim3(BATCH/256), dim3(256), 0, stream>>>(
            N, X, P, Wr1, br1, Wr2, br2, cA, dA, phiF, out, full);
    } else {
        k_fused<<<dim3(BATCH/256), dim3(256), 0, stream>>>(
            N, X, P, Tarr, dB, Wr1, br1, Wr2, br2,
            Wg1, bg1, Wg2, bg2, Wj1, bj1, Wj2, bj2, out, full);
    }
}